// Round 6
// baseline (16314.119 us; speedup 1.0000x reference)
//
#include <hip/hip_runtime.h>
#include <stdint.h>

#define B_   512
#define H_   1024
#define S_   128
#define OUT_ 49
#define NWG_ 193

typedef __attribute__((ext_vector_type(8)))  short short8;
typedef __attribute__((ext_vector_type(4)))  float f32x4;
typedef __attribute__((ext_vector_type(16))) float f32x16;

#define VMW(n) asm volatile("s_waitcnt vmcnt(" #n ")" ::: "memory")

__device__ __forceinline__ unsigned short f2bf(float f) {
  union { float f; uint32_t u; } v; v.f = f;
  return (unsigned short)((v.u + 0x7FFFu + ((v.u >> 16) & 1u)) >> 16);  // RNE
}
__device__ __forceinline__ float sigf(float x)   { return 1.0f / (1.0f + __expf(-x)); }
__device__ __forceinline__ float tanhf_(float x) { return 2.0f / (1.0f + __expf(-2.0f * x)) - 1.0f; }

__device__ __forceinline__ void gload16(const void* gp, void* lp) {
  __builtin_amdgcn_global_load_lds(
      (const __attribute__((address_space(1))) void*)gp,
      (__attribute__((address_space(3))) void*)lp, 16, 0, 0);
}

// ---------------------------------------------------------------------------
// n' packing for gate weights: n' = hb16*64 + gp*32 + j*16 + hc
//   gate = gp*2 + j (i,f,g,o), hidden h = hb16*16 + hc.
// Frag-linear dst: [nt(128)][ks(64)][lane(64)][e(8)] bf16,
//   B[n' = nt*32 + (l&31)][k = ks*16 + (l>>5)*8 + e]   (32x32x16 B-operand)
// ---------------------------------------------------------------------------
__global__ void pack_gate_kernel(const float* __restrict__ src, unsigned short* __restrict__ dst) {
  int gid = blockIdx.x * blockDim.x + threadIdx.x;       // 128*64*64 = 524288
  int l  = gid & 63;
  int ks = (gid >> 6) & 63;
  int nt = gid >> 12;
  int np = nt * 32 + (l & 31);
  int hb = np >> 6, r6 = np & 63;
  int gate = (r6 >> 5) * 2 + ((r6 >> 4) & 1);
  int h = hb * 16 + (np & 15);
  int kk = ks * 16 + (l >> 5) * 8;
  const float* p = src + (size_t)(gate * 1024 + h) * 1024 + kk;
  short8 v;
#pragma unroll
  for (int e = 0; e < 8; ++e) v[e] = (short)f2bf(p[e]);
  *reinterpret_cast<short8*>(dst + (size_t)gid * 8) = v;
}

// natural-order frag pack (row = nt*32 + (l&31)); rows >= nrows zero-padded.
__global__ void pack_nat_kernel(const float* __restrict__ src, unsigned short* __restrict__ dst,
                                int NT, int KS, int C, int rowoff, int nrows) {
  int gid = blockIdx.x * blockDim.x + threadIdx.x;
  int total = NT * KS * 64;
  if (gid >= total) return;
  int l  = gid & 63;
  int ks = (gid >> 6) % KS;
  int nt = gid / (KS * 64);
  int row = nt * 32 + (l & 31);
  int kk = ks * 16 + (l >> 5) * 8;
  short8 v;
  if (row < nrows) {
    const float* p = src + (size_t)(rowoff + row) * C + kk;
#pragma unroll
    for (int e = 0; e < 8; ++e) v[e] = (short)f2bf(p[e]);
  } else {
#pragma unroll
    for (int e = 0; e < 8; ++e) v[e] = 0;
  }
  *reinterpret_cast<short8*>(dst + (size_t)gid * 8) = v;
}

__global__ void prep_bias_kernel(const float* __restrict__ bi0, const float* __restrict__ bh0,
                                 const float* __restrict__ bi1, const float* __restrict__ bh1,
                                 float* __restrict__ b0p, float* __restrict__ b1p) {
  int np = blockIdx.x * blockDim.x + threadIdx.x;
  if (np < 4096) {
    int hb = np >> 6, r6 = np & 63;
    int gate = (r6 >> 5) * 2 + ((r6 >> 4) & 1);
    int s = gate * 1024 + hb * 16 + (np & 15);
    b0p[np] = bi0[s] + bh0[s];
    b1p[np] = bi1[s] + bh1[s];
  }
}

// ---------------------------------------------------------------------------
// init: h0/c0 = z @ W^T + b for both layers, K=64 via MFMA.
// h written in A-frag layout (slot 1); c written in C/D-frag layout (2 replicas).
// (verified correct on HW in R4)
// ---------------------------------------------------------------------------
__global__ __launch_bounds__(256) void init_gemm_kernel(
    const unsigned short* __restrict__ zf, const unsigned short* __restrict__ wip,
    const float* __restrict__ b_hid, const float* __restrict__ b_cell,
    char* __restrict__ h1f, char* __restrict__ h2f,
    char* __restrict__ c0f, char* __restrict__ c1f) {
  __shared__ char tl[8192];
  const int bid = blockIdx.x;                 // 64: layer(2) x nt32(32)
  const int layer = bid >> 5, nt32 = bid & 31;
  const int tid = threadIdx.x, w = tid >> 6, l = tid & 63;
  const unsigned short* wh_ = wip + (size_t)layer * 65536;          // hid frags
  const unsigned short* wc_ = wip + (size_t)(2 + layer) * 65536;    // cell frags
  const float bh = b_hid[layer * 1024 + nt32 * 32 + (l & 31)];
  const float bc = b_cell[layer * 1024 + nt32 * 32 + (l & 31)];
  f32x16 ah[4], ac[4];
#pragma unroll
  for (int m = 0; m < 4; ++m) { ah[m] = (f32x16)0.0f; ac[m] = (f32x16)0.0f; }
#pragma unroll
  for (int ks = 0; ks < 4; ++ks) {
    short8 bhf = *reinterpret_cast<const short8*>((const char*)wh_ + ((size_t)(nt32 * 4 + ks) * 64 + l) * 16);
    short8 bcf = *reinterpret_cast<const short8*>((const char*)wc_ + ((size_t)(nt32 * 4 + ks) * 64 + l) * 16);
#pragma unroll
    for (int m = 0; m < 4; ++m) {
      short8 a = *reinterpret_cast<const short8*>((const char*)zf + ((size_t)((w * 4 + m) * 4 + ks) * 64 + l) * 16);
      ah[m] = __builtin_amdgcn_mfma_f32_32x32x16_bf16(a, bhf, ah[m], 0, 0, 0);
      ac[m] = __builtin_amdgcn_mfma_f32_32x32x16_bf16(a, bcf, ac[m], 0, 0, 0);
    }
  }
  char* hf  = layer ? h2f : h1f;
  char* cfb = layer ? c1f : c0f;
  const int khalf = l >> 5;
#pragma unroll
  for (int m = 0; m < 4; ++m) {
    const int gmt = w * 4 + m;
#pragma unroll
    for (int r = 0; r < 16; ++r) { ah[m][r] += bh; ac[m][r] += bc; }
    // c -> C/D-frag layout, replicated over lane-bit4
    int hb16c = nt32 * 2 + ((l >> 4) & 1);
    int lt = (l & 15) + 32 * khalf;
    float* cb0 = (float*)(cfb + (((size_t)hb16c * 16 + gmt) * 64 + lt) * 64);
    float* cb1 = (float*)(cfb + (((size_t)hb16c * 16 + gmt) * 64 + lt + 16) * 64);
#pragma unroll
    for (int q = 0; q < 4; ++q) {
      f32x4 v = { ac[m][q * 4], ac[m][q * 4 + 1], ac[m][q * 4 + 2], ac[m][q * 4 + 3] };
      *(f32x4*)(cb0 + q * 4) = v;
      *(f32x4*)(cb1 + q * 4) = v;
    }
    // h -> A-frag layout via per-wave LDS transpose tile
#pragma unroll
    for (int r = 0; r < 16; ++r) {
      int rr = (r & 3) + 8 * (r >> 2) + 4 * khalf;
      *(unsigned short*)(tl + w * 2048 + rr * 64 + (l & 31) * 2) = f2bf(ah[m][r]);
    }
#pragma unroll
    for (int s = 0; s < 2; ++s) {
      short8 hv = *reinterpret_cast<const short8*>(tl + w * 2048 + (l & 31) * 64 + s * 32 + khalf * 16);
      *reinterpret_cast<short8*>(hf + 1048576 + (((size_t)gmt * 64 + nt32 * 2 + s) * 64 + l) * 16) = hv;
    }
  }
}

// ---------------------------------------------------------------------------
// Persistent kernel v2: 193 WGs x 512 threads (8 waves), weights in LDS.
//  bid [0,64):    role 0 = L0    t=k      A=h1f[(t+1)&1] -> h1f[t&1], c0
//  bid [64,128):  role 1 = L1h   t=k-2    A=h2f[(t+1)&1] + xp[t&1] -> h2f, c1
//  bid [128,192): role 2 = L1x   t=k-1    A=h1f[t&1] -> xp[t&1] (raw f32)
//  bid 192:       role 3 = proj  t=k-3    A=h2f[t&1] -> out
// Each WG: 64 n' cols (2 nt-frags, 128 KiB weights staged ONCE into LDS),
// full M=512: wave w does m-tiles {2w, 2w+1}. A streamed via 4-deep reg
// prefetch (static-indexed). acc 64 + pf 32 VGPRs -> no spill.
// LDS: [0,128K) weights; [128K,144K) per-wave epilogue transpose tiles.
// ---------------------------------------------------------------------------
__global__ __launch_bounds__(512, 2) void persist_kernel(
    const unsigned short* __restrict__ w0pk, const unsigned short* __restrict__ w1hpk,
    const unsigned short* __restrict__ w1xpk, const unsigned short* __restrict__ woutpk,
    const float* __restrict__ b0p, const float* __restrict__ b1p, const float* __restrict__ b_out,
    char* __restrict__ h1f, char* __restrict__ h2f, char* __restrict__ xp,
    char* __restrict__ c0f, char* __restrict__ c1f,
    float* __restrict__ out, int* __restrict__ flags) {
  extern __shared__ char smem[];
  char* WLDS = smem;                       // 128 KiB: [nt(2)][ks(64)][lane(64)][16B]
  const int bid = blockIdx.x, tid = threadIdx.x;
  const int w = tid >> 6, l = tid & 63;
  char* tl = smem + 131072 + w * 2048;     // per-wave 2 KiB transpose scratch

  int role, hb16 = 0;
  const unsigned short* wsrc;
  if (bid < 64)       { role = 0; hb16 = bid;       wsrc = w0pk;  }
  else if (bid < 128) { role = 1; hb16 = bid - 64;  wsrc = w1hpk; }
  else if (bid < 192) { role = 2; hb16 = bid - 128; wsrc = w1xpk; }
  else                { role = 3; wsrc = woutpk; }

  // ---- stage this WG's 128 KiB weight slice into LDS (once) ----
  // gload16 contract: LDS dest must be WAVE-UNIFORM (HW adds lane*16);
  // global src is per-lane.
  {
    const char* src = (const char*)wsrc + (role == 3 ? 0 : (size_t)hb16 * 131072);
#pragma unroll
    for (int i = 0; i < 16; ++i)
      gload16(src + ((size_t)(i * 512 + w * 64 + l)) * 16,
              WLDS + (i * 512 + w * 64) * 16);
    VMW(0);
  }

  float bias0 = 0.f, bias1 = 0.f, bo0 = 0.f, bo1 = 0.f;
  char* hb_base = nullptr; char* cfb = nullptr;
  if (role == 0) { hb_base = h1f; cfb = c0f; bias0 = b0p[hb16*64 + (l&31)]; bias1 = b0p[hb16*64 + 32 + (l&31)]; }
  if (role == 1) { hb_base = h2f; cfb = c1f; bias0 = b1p[hb16*64 + (l&31)]; bias1 = b1p[hb16*64 + 32 + (l&31)]; }
  if (role == 3) {
    int o0 = l & 31, o1 = 32 + (l & 31);
    bo0 = (o0 < OUT_) ? b_out[o0] : 0.f;
    bo1 = (o1 < OUT_) ? b_out[o1] : 0.f;
  }
  __syncthreads();

  const int gmt0 = w * 2;
  const int j16 = (l >> 4) & 1, khalf = l >> 5, hc = l & 15;

  for (int k = 0; k < 131; ++k) {
    const int t = k - (role == 0 ? 0 : role == 2 ? 1 : role == 1 ? 2 : 3);
    if (t >= 0 && t < 128) {
      const char* Ab;
      if (role == 0)      Ab = h1f + (size_t)((t + 1) & 1) * 1048576;
      else if (role == 2) Ab = h1f + (size_t)(t & 1) * 1048576;
      else if (role == 1) Ab = h2f + (size_t)((t + 1) & 1) * 1048576;
      else                Ab = h2f + (size_t)(t & 1) * 1048576;

      // ================= GEMM core: 2 m-tiles x 2 n-tiles x K=1024 =================
      f32x16 acc0[2], acc1[2];
#pragma unroll
      for (int m = 0; m < 2; ++m) { acc0[m] = (f32x16)0.0f; acc1[m] = (f32x16)0.0f; }
      short8 pf[4][2];                       // 4-deep A prefetch (static-indexed)
#pragma unroll
      for (int d = 0; d < 4; ++d)
#pragma unroll
        for (int m = 0; m < 2; ++m)
          pf[d][m] = *reinterpret_cast<const short8*>(
              Ab + (((size_t)(gmt0 + m) * 64 + d) * 64 + l) * 16);
      for (int kq = 0; kq < 16; ++kq) {
        const bool pfon = (kq < 15);
#pragma unroll
        for (int ksl = 0; ksl < 4; ++ksl) {
          const int ks = kq * 4 + ksl;
          short8 b0f = *reinterpret_cast<const short8*>(WLDS + (size_t)ks * 1024 + l * 16);
          short8 b1f = *reinterpret_cast<const short8*>(WLDS + 65536 + (size_t)ks * 1024 + l * 16);
#pragma unroll
          for (int m = 0; m < 2; ++m) {
            acc0[m] = __builtin_amdgcn_mfma_f32_32x32x16_bf16(pf[ksl][m], b0f, acc0[m], 0, 0, 0);
            acc1[m] = __builtin_amdgcn_mfma_f32_32x32x16_bf16(pf[ksl][m], b1f, acc1[m], 0, 0, 0);
          }
          if (pfon) {
#pragma unroll
            for (int m = 0; m < 2; ++m)
              pf[ksl][m] = *reinterpret_cast<const short8*>(
                  Ab + (((size_t)(gmt0 + m) * 64 + ks + 4) * 64 + l) * 16);
          }
        }
      }

      // ================= epilogues =================
      if (role <= 1) {
        char* Ho = hb_base + (size_t)(t & 1) * 1048576;
        const char* xpb = xp + (size_t)(t & 1) * 8388608;
#pragma unroll
        for (int m = 0; m < 2; ++m) {
          const int gmt = gmt0 + m;
          f32x16 p0 = acc0[m], p1 = acc1[m];
#pragma unroll
          for (int r = 0; r < 16; ++r) { p0[r] += bias0; p1[r] += bias1; }
          if (role == 1) {
            const float* x0 = (const float*)(xpb + (((size_t)(hb16 * 2) * 16 + gmt) * 64 + l) * 64);
            const float* x1 = (const float*)(xpb + (((size_t)(hb16 * 2 + 1) * 16 + gmt) * 64 + l) * 64);
#pragma unroll
            for (int q = 0; q < 4; ++q) {
              f32x4 v0 = *(const f32x4*)(x0 + q * 4);
              f32x4 v1 = *(const f32x4*)(x1 + q * 4);
#pragma unroll
              for (int e = 0; e < 4; ++e) { p0[q * 4 + e] += v0[e]; p1[q * 4 + e] += v1[e]; }
            }
          }
          float* cb = (float*)(cfb + (((size_t)hb16 * 16 + gmt) * 64 + l) * 64);
          f32x4 cq[4];
#pragma unroll
          for (int q = 0; q < 4; ++q) cq[q] = *(const f32x4*)(cb + q * 4);
#pragma unroll
          for (int r = 0; r < 16; ++r) {
            float a0 = p0[r], a1 = p1[r];
            float y0 = __shfl_xor(a0, 16);
            float y1 = __shfl_xor(a1, 16);
            float vi = j16 ? y0 : a0;
            float vf = j16 ? a0 : y0;
            float vg = j16 ? y1 : a1;
            float vo = j16 ? a1 : y1;
            float co = cq[r >> 2][r & 3];
            float cn = sigf(vf) * co + sigf(vi) * tanhf_(vg);
            cq[r >> 2][r & 3] = cn;
            float hv = sigf(vo) * tanhf_(cn);
            const int rr = (r & 3) + 8 * (r >> 2) + 4 * khalf;
            *(unsigned short*)(tl + m * 1024 + rr * 32 + hc * 2) = f2bf(hv);
          }
#pragma unroll
          for (int q = 0; q < 4; ++q) *(f32x4*)(cb + q * 4) = cq[q];
        }
#pragma unroll
        for (int m = 0; m < 2; ++m) {
          short8 hv = *reinterpret_cast<const short8*>(tl + m * 1024 + (l & 31) * 32 + khalf * 16);
          *reinterpret_cast<short8*>(Ho + (((size_t)(gmt0 + m) * 64 + hb16) * 64 + l) * 16) = hv;
        }
      } else if (role == 2) {
        char* xpo = xp + (size_t)(t & 1) * 8388608;
#pragma unroll
        for (int m = 0; m < 2; ++m) {
          float* xo0 = (float*)(xpo + (((size_t)(hb16 * 2) * 16 + gmt0 + m) * 64 + l) * 64);
          float* xo1 = (float*)(xpo + (((size_t)(hb16 * 2 + 1) * 16 + gmt0 + m) * 64 + l) * 64);
#pragma unroll
          for (int q = 0; q < 4; ++q) {
            f32x4 v0 = { acc0[m][q * 4], acc0[m][q * 4 + 1], acc0[m][q * 4 + 2], acc0[m][q * 4 + 3] };
            f32x4 v1 = { acc1[m][q * 4], acc1[m][q * 4 + 1], acc1[m][q * 4 + 2], acc1[m][q * 4 + 3] };
            *(f32x4*)(xo0 + q * 4) = v0;
            *(f32x4*)(xo1 + q * 4) = v1;
          }
        }
      } else {
#pragma unroll
        for (int m = 0; m < 2; ++m) {
#pragma unroll
          for (int nt = 0; nt < 2; ++nt) {
            const int o = nt * 32 + (l & 31);
            const float bov = nt ? bo1 : bo0;
            if (o < OUT_) {
#pragma unroll
              for (int r = 0; r < 16; ++r) {
                const int rr = (r & 3) + 8 * (r >> 2) + 4 * khalf;
                const int bb = (gmt0 + m) * 32 + rr;
                const float pa = nt ? acc1[m][r] : acc0[m][r];
                out[((size_t)bb * S_ + t) * OUT_ + o] = sigf(pa + bov);
              }
            }
          }
        }
      }
    }
    // ---- grid barrier (validated on HW in R4) ----
    __threadfence();
    __syncthreads();
    if (tid == 0) {
      atomicAdd(&flags[k * 4 + (bid & 3)], 1);
      int guard = 0;
      while (true) {
        int s = __hip_atomic_load(&flags[k * 4 + 0], __ATOMIC_RELAXED, __HIP_MEMORY_SCOPE_AGENT)
              + __hip_atomic_load(&flags[k * 4 + 1], __ATOMIC_RELAXED, __HIP_MEMORY_SCOPE_AGENT)
              + __hip_atomic_load(&flags[k * 4 + 2], __ATOMIC_RELAXED, __HIP_MEMORY_SCOPE_AGENT)
              + __hip_atomic_load(&flags[k * 4 + 3], __ATOMIC_RELAXED, __HIP_MEMORY_SCOPE_AGENT);
        if (s >= NWG_) break;
        __builtin_amdgcn_s_sleep(2);
        if (++guard > (1 << 20)) break;   // bail-out: never hangs the harness
      }
    }
    __syncthreads();
    __threadfence();
  }
}

// ---------------------------------------------------------------------------
extern "C" void kernel_launch(void* const* d_in, const int* in_sizes, int n_in,
                              void* d_out, int out_size, void* d_ws, size_t ws_size,
                              hipStream_t stream) {
  const float* z      = (const float*)d_in[0];
  const float* W_hid  = (const float*)d_in[1];
  const float* b_hid  = (const float*)d_in[2];
  const float* W_cell = (const float*)d_in[3];
  const float* b_cell = (const float*)d_in[4];
  // d_in[5] = W_ih0: multiplied by zeros in the reference -> unused
  const float* W_hh0  = (const float*)d_in[6];
  const float* b_ih0  = (const float*)d_in[7];
  const float* b_hh0  = (const float*)d_in[8];
  const float* W_ih1  = (const float*)d_in[9];
  const float* W_hh1  = (const float*)d_in[10];
  const float* b_ih1  = (const float*)d_in[11];
  const float* b_hh1  = (const float*)d_in[12];
  const float* W_out  = (const float*)d_in[13];
  const float* b_out  = (const float*)d_in[14];
  float* out = (float*)d_out;

  char* ws = (char*)d_ws;
  int*            FLAGS = (int*)(ws + 0);                         // 4 KiB
  float*          B0P   = (float*)(ws + 4096);                    // 16 KiB
  float*          B1P   = (float*)(ws + 20480);                   // 16 KiB
  unsigned short* WOUTp = (unsigned short*)(ws + 65536);          // 128 KiB
  unsigned short* ZFp   = (unsigned short*)(ws + 196608);         // 64 KiB
  unsigned short* WIp   = (unsigned short*)(ws + 262144);         // 512 KiB
  unsigned short* W0p   = (unsigned short*)(ws + (1ull << 20));   // 8 MiB
  unsigned short* W1Hp  = (unsigned short*)(ws + (9ull << 20));   // 8 MiB
  unsigned short* W1Xp  = (unsigned short*)(ws + (17ull << 20));  // 8 MiB
  char*           H1F   = ws + (25ull << 20);                     // 2 MiB (2 slots)
  char*           H2F   = ws + (27ull << 20);                     // 2 MiB
  char*           XP    = ws + (29ull << 20);                     // 16 MiB (2 slots)
  char*           C0F   = ws + (45ull << 20);                     // 4 MiB
  char*           C1F   = ws + (49ull << 20);                     // 4 MiB

  hipMemsetAsync(FLAGS, 0, 4096, stream);
  pack_gate_kernel<<<2048, 256, 0, stream>>>(W_hh0, W0p);
  pack_gate_kernel<<<2048, 256, 0, stream>>>(W_hh1, W1Hp);
  pack_gate_kernel<<<2048, 256, 0, stream>>>(W_ih1, W1Xp);
  pack_nat_kernel<<<32, 256, 0, stream>>>(W_out, WOUTp, 2, 64, 1024, 0, 49);
  pack_nat_kernel<<<16, 256, 0, stream>>>(z, ZFp, 16, 4, 64, 0, 512);
  pack_nat_kernel<<<32, 256, 0, stream>>>(W_hid,  WIp,          32, 4, 64, 0,    1024);
  pack_nat_kernel<<<32, 256, 0, stream>>>(W_hid,  WIp + 65536,  32, 4, 64, 1024, 1024);
  pack_nat_kernel<<<32, 256, 0, stream>>>(W_cell, WIp + 131072, 32, 4, 64, 0,    1024);
  pack_nat_kernel<<<32, 256, 0, stream>>>(W_cell, WIp + 196608, 32, 4, 64, 1024, 1024);
  prep_bias_kernel<<<16, 256, 0, stream>>>(b_ih0, b_hh0, b_ih1, b_hh1, B0P, B1P);
  init_gemm_kernel<<<64, 256, 0, stream>>>(ZFp, WIp, b_hid, b_cell, H1F, H2F, C0F, C1F);

  static bool attr_set = false;
  if (!attr_set) {
    hipFuncSetAttribute((const void*)persist_kernel,
                        hipFuncAttributeMaxDynamicSharedMemorySize, 147456);
    attr_set = true;
  }
  persist_kernel<<<NWG_, 512, 147456, stream>>>(
      W0p, W1Hp, W1Xp, WOUTp, B0P, B1P, b_out,
      H1F, H2F, XP, C0F, C1F, out, FLAGS);
}

// Round 7
// 5051.872 us; speedup vs baseline: 3.2293x; 3.2293x over previous
//
#include <hip/hip_runtime.h>
#include <stdint.h>

#define B_   512
#define H_   1024
#define S_   128
#define OUT_ 49
#define NWG_ 193

typedef __attribute__((ext_vector_type(8)))  short short8;
typedef __attribute__((ext_vector_type(4)))  float f32x4;
typedef __attribute__((ext_vector_type(16))) float f32x16;

#define VMW(n) asm volatile("s_waitcnt vmcnt(" #n ")" ::: "memory")

__device__ __forceinline__ unsigned short f2bf(float f) {
  union { float f; uint32_t u; } v; v.f = f;
  return (unsigned short)((v.u + 0x7FFFu + ((v.u >> 16) & 1u)) >> 16);  // RNE
}
__device__ __forceinline__ float sigf(float x)   { return 1.0f / (1.0f + __expf(-x)); }
__device__ __forceinline__ float tanhf_(float x) { return 2.0f / (1.0f + __expf(-2.0f * x)) - 1.0f; }

__device__ __forceinline__ void gload16(const void* gp, void* lp) {
  __builtin_amdgcn_global_load_lds(
      (const __attribute__((address_space(1))) void*)gp,
      (__attribute__((address_space(3))) void*)lp, 16, 0, 0);
}

// ---------------------------------------------------------------------------
// n' packing for gate weights: n' = hb16*64 + gp*32 + j*16 + hc
//   gate = gp*2 + j (i,f,g,o), hidden h = hb16*16 + hc.
// Frag-linear dst: [nt(128)][ks(64)][lane(64)][e(8)] bf16,
//   B[n' = nt*32 + (l&31)][k = ks*16 + (l>>5)*8 + e]   (32x32x16 B-operand)
// (HW-verified R4/R6)
// ---------------------------------------------------------------------------
__global__ void pack_gate_kernel(const float* __restrict__ src, unsigned short* __restrict__ dst) {
  int gid = blockIdx.x * blockDim.x + threadIdx.x;       // 128*64*64 = 524288
  int l  = gid & 63;
  int ks = (gid >> 6) & 63;
  int nt = gid >> 12;
  int np = nt * 32 + (l & 31);
  int hb = np >> 6, r6 = np & 63;
  int gate = (r6 >> 5) * 2 + ((r6 >> 4) & 1);
  int h = hb * 16 + (np & 15);
  int kk = ks * 16 + (l >> 5) * 8;
  const float* p = src + (size_t)(gate * 1024 + h) * 1024 + kk;
  short8 v;
#pragma unroll
  for (int e = 0; e < 8; ++e) v[e] = (short)f2bf(p[e]);
  *reinterpret_cast<short8*>(dst + (size_t)gid * 8) = v;
}

// natural-order frag pack (row = nt*32 + (l&31)); rows >= nrows zero-padded.
__global__ void pack_nat_kernel(const float* __restrict__ src, unsigned short* __restrict__ dst,
                                int NT, int KS, int C, int rowoff, int nrows) {
  int gid = blockIdx.x * blockDim.x + threadIdx.x;
  int total = NT * KS * 64;
  if (gid >= total) return;
  int l  = gid & 63;
  int ks = (gid >> 6) % KS;
  int nt = gid / (KS * 64);
  int row = nt * 32 + (l & 31);
  int kk = ks * 16 + (l >> 5) * 8;
  short8 v;
  if (row < nrows) {
    const float* p = src + (size_t)(rowoff + row) * C + kk;
#pragma unroll
    for (int e = 0; e < 8; ++e) v[e] = (short)f2bf(p[e]);
  } else {
#pragma unroll
    for (int e = 0; e < 8; ++e) v[e] = 0;
  }
  *reinterpret_cast<short8*>(dst + (size_t)gid * 8) = v;
}

__global__ void prep_bias_kernel(const float* __restrict__ bi0, const float* __restrict__ bh0,
                                 const float* __restrict__ bi1, const float* __restrict__ bh1,
                                 float* __restrict__ b0p, float* __restrict__ b1p) {
  int np = blockIdx.x * blockDim.x + threadIdx.x;
  if (np < 4096) {
    int hb = np >> 6, r6 = np & 63;
    int gate = (r6 >> 5) * 2 + ((r6 >> 4) & 1);
    int s = gate * 1024 + hb * 16 + (np & 15);
    b0p[np] = bi0[s] + bh0[s];
    b1p[np] = bi1[s] + bh1[s];
  }
}

// ---------------------------------------------------------------------------
// init: h0/c0 = z @ W^T + b for both layers, K=64 via MFMA. (HW-verified R4/R6)
// ---------------------------------------------------------------------------
__global__ __launch_bounds__(256) void init_gemm_kernel(
    const unsigned short* __restrict__ zf, const unsigned short* __restrict__ wip,
    const float* __restrict__ b_hid, const float* __restrict__ b_cell,
    char* __restrict__ h1f, char* __restrict__ h2f,
    char* __restrict__ c0f, char* __restrict__ c1f) {
  __shared__ char tl[8192];
  const int bid = blockIdx.x;                 // 64: layer(2) x nt32(32)
  const int layer = bid >> 5, nt32 = bid & 31;
  const int tid = threadIdx.x, w = tid >> 6, l = tid & 63;
  const unsigned short* wh_ = wip + (size_t)layer * 65536;          // hid frags
  const unsigned short* wc_ = wip + (size_t)(2 + layer) * 65536;    // cell frags
  const float bh = b_hid[layer * 1024 + nt32 * 32 + (l & 31)];
  const float bc = b_cell[layer * 1024 + nt32 * 32 + (l & 31)];
  f32x16 ah[4], ac[4];
#pragma unroll
  for (int m = 0; m < 4; ++m) { ah[m] = (f32x16)0.0f; ac[m] = (f32x16)0.0f; }
#pragma unroll
  for (int ks = 0; ks < 4; ++ks) {
    short8 bhf = *reinterpret_cast<const short8*>((const char*)wh_ + ((size_t)(nt32 * 4 + ks) * 64 + l) * 16);
    short8 bcf = *reinterpret_cast<const short8*>((const char*)wc_ + ((size_t)(nt32 * 4 + ks) * 64 + l) * 16);
#pragma unroll
    for (int m = 0; m < 4; ++m) {
      short8 a = *reinterpret_cast<const short8*>((const char*)zf + ((size_t)((w * 4 + m) * 4 + ks) * 64 + l) * 16);
      ah[m] = __builtin_amdgcn_mfma_f32_32x32x16_bf16(a, bhf, ah[m], 0, 0, 0);
      ac[m] = __builtin_amdgcn_mfma_f32_32x32x16_bf16(a, bcf, ac[m], 0, 0, 0);
    }
  }
  char* hf  = layer ? h2f : h1f;
  char* cfb = layer ? c1f : c0f;
  const int khalf = l >> 5;
#pragma unroll
  for (int m = 0; m < 4; ++m) {
    const int gmt = w * 4 + m;
#pragma unroll
    for (int r = 0; r < 16; ++r) { ah[m][r] += bh; ac[m][r] += bc; }
    int hb16c = nt32 * 2 + ((l >> 4) & 1);
    int lt = (l & 15) + 32 * khalf;
    float* cb0 = (float*)(cfb + (((size_t)hb16c * 16 + gmt) * 64 + lt) * 64);
    float* cb1 = (float*)(cfb + (((size_t)hb16c * 16 + gmt) * 64 + lt + 16) * 64);
#pragma unroll
    for (int q = 0; q < 4; ++q) {
      f32x4 v = { ac[m][q * 4], ac[m][q * 4 + 1], ac[m][q * 4 + 2], ac[m][q * 4 + 3] };
      *(f32x4*)(cb0 + q * 4) = v;
      *(f32x4*)(cb1 + q * 4) = v;
    }
#pragma unroll
    for (int r = 0; r < 16; ++r) {
      int rr = (r & 3) + 8 * (r >> 2) + 4 * khalf;
      *(unsigned short*)(tl + w * 2048 + rr * 64 + (l & 31) * 2) = f2bf(ah[m][r]);
    }
#pragma unroll
    for (int s = 0; s < 2; ++s) {
      short8 hv = *reinterpret_cast<const short8*>(tl + w * 2048 + (l & 31) * 64 + s * 32 + khalf * 16);
      *reinterpret_cast<short8*>(hf + 1048576 + (((size_t)gmt * 64 + nt32 * 2 + s) * 64 + l) * 16) = hv;
    }
  }
}

// ---------------------------------------------------------------------------
// Super-step kernel (one LAUNCH per k; launch boundary = the fence).
//  bid [0,64):    role 0 = L0    t=k      A=h1f[(t+1)&1] -> h1f[t&1], c0
//  bid [64,128):  role 1 = L1h   t=k-2    A=h2f[(t+1)&1] + xp[t&1] -> h2f, c1
//  bid [128,192): role 2 = L1x   t=k-1    A=h1f[t&1] -> xp[t&1] (raw f32)
//  bid 192:       role 3 = proj  t=k-3    A=h2f[t&1] -> out
// Each WG: stage 128 KiB weights -> LDS (once per launch), then barrier-free
// K-loop: A streamed via 8-deep static-indexed register prefetch.
// LDS: [0,128K) weights; [128K,144K) per-wave epilogue transpose tiles.
// ---------------------------------------------------------------------------
__global__ __launch_bounds__(512, 2) void step_kernel(
    int k,
    const unsigned short* __restrict__ w0pk, const unsigned short* __restrict__ w1hpk,
    const unsigned short* __restrict__ w1xpk, const unsigned short* __restrict__ woutpk,
    const float* __restrict__ b0p, const float* __restrict__ b1p, const float* __restrict__ b_out,
    char* __restrict__ h1f, char* __restrict__ h2f, char* __restrict__ xp,
    char* __restrict__ c0f, char* __restrict__ c1f,
    float* __restrict__ out) {
  extern __shared__ char smem[];
  char* WLDS = smem;                       // 128 KiB: [nt(2)][ks(64)][lane(64)][16B]
  const int bid = blockIdx.x, tid = threadIdx.x;
  const int w = tid >> 6, l = tid & 63;
  char* tl = smem + 131072 + w * 2048;     // per-wave 2 KiB transpose scratch

  int role, hb16 = 0;
  const unsigned short* wsrc;
  if (bid < 64)       { role = 0; hb16 = bid;       wsrc = w0pk;  }
  else if (bid < 128) { role = 1; hb16 = bid - 64;  wsrc = w1hpk; }
  else if (bid < 192) { role = 2; hb16 = bid - 128; wsrc = w1xpk; }
  else                { role = 3; wsrc = woutpk; }

  const int t = k - (role == 0 ? 0 : role == 2 ? 1 : role == 1 ? 2 : 3);
  if (t < 0 || t > 127) return;            // idle role this launch

  const char* Ab;
  if (role == 0)      Ab = h1f + (size_t)((t + 1) & 1) * 1048576;
  else if (role == 2) Ab = h1f + (size_t)(t & 1) * 1048576;
  else if (role == 1) Ab = h2f + (size_t)((t + 1) & 1) * 1048576;
  else                Ab = h2f + (size_t)(t & 1) * 1048576;

  const int gmt0 = w * 2;

  // ---- stage this WG's 128 KiB weight slice into LDS ----
  // gload16 contract: LDS dest WAVE-UNIFORM (HW adds lane*16); global src per-lane.
  {
    const char* src = (const char*)wsrc + (role == 3 ? 0 : (size_t)hb16 * 131072);
#pragma unroll
    for (int i = 0; i < 16; ++i)
      gload16(src + ((size_t)(i * 512 + w * 64 + l)) * 16,
              WLDS + (i * 512 + w * 64) * 16);
  }
  // ---- prime 8-deep A prefetch (overlaps weight-stage latency) ----
  short8 pf[8][2];
#pragma unroll
  for (int d = 0; d < 8; ++d)
#pragma unroll
    for (int m = 0; m < 2; ++m)
      pf[d][m] = *reinterpret_cast<const short8*>(
          Ab + (((size_t)(gmt0 + m) * 64 + d) * 64 + l) * 16);
  VMW(16);                                 // the 16 weight-stage ops retired
  __syncthreads();                         // all waves' slices visible

  float bias0 = 0.f, bias1 = 0.f, bo0 = 0.f, bo1 = 0.f;
  char* cfb = nullptr;
  if (role == 0) { cfb = c0f; bias0 = b0p[hb16*64 + (l&31)]; bias1 = b0p[hb16*64 + 32 + (l&31)]; }
  if (role == 1) { cfb = c1f; bias0 = b1p[hb16*64 + (l&31)]; bias1 = b1p[hb16*64 + 32 + (l&31)]; }
  if (role == 3) {
    int o0 = l & 31, o1 = 32 + (l & 31);
    bo0 = (o0 < OUT_) ? b_out[o0] : 0.f;
    bo1 = (o1 < OUT_) ? b_out[o1] : 0.f;
  }

  const int j16 = (l >> 4) & 1, khalf = l >> 5, hc = l & 15;

  // ================= GEMM core: 2 m-tiles x 2 n-tiles x K=1024 =================
  f32x16 acc0[2], acc1[2];
#pragma unroll
  for (int m = 0; m < 2; ++m) { acc0[m] = (f32x16)0.0f; acc1[m] = (f32x16)0.0f; }
  for (int kq = 0; kq < 8; ++kq) {
    const bool pfon = (kq < 7);
#pragma unroll
    for (int ksl = 0; ksl < 8; ++ksl) {
      const int ks = kq * 8 + ksl;
      short8 b0f = *reinterpret_cast<const short8*>(WLDS + (size_t)ks * 1024 + l * 16);
      short8 b1f = *reinterpret_cast<const short8*>(WLDS + 65536 + (size_t)ks * 1024 + l * 16);
#pragma unroll
      for (int m = 0; m < 2; ++m) {
        acc0[m] = __builtin_amdgcn_mfma_f32_32x32x16_bf16(pf[ksl][m], b0f, acc0[m], 0, 0, 0);
        acc1[m] = __builtin_amdgcn_mfma_f32_32x32x16_bf16(pf[ksl][m], b1f, acc1[m], 0, 0, 0);
      }
      if (pfon) {
#pragma unroll
        for (int m = 0; m < 2; ++m)
          pf[ksl][m] = *reinterpret_cast<const short8*>(
              Ab + (((size_t)(gmt0 + m) * 64 + ks + 8) * 64 + l) * 16);
      }
    }
  }

  // ================= epilogues =================
  if (role <= 1) {
    char* Ho = (role ? h2f : h1f) + (size_t)(t & 1) * 1048576;
    const char* xpb = xp + (size_t)(t & 1) * 8388608;
#pragma unroll
    for (int m = 0; m < 2; ++m) {
      const int gmt = gmt0 + m;
      f32x16 p0 = acc0[m], p1 = acc1[m];
#pragma unroll
      for (int r = 0; r < 16; ++r) { p0[r] += bias0; p1[r] += bias1; }
      if (role == 1) {
        const float* x0 = (const float*)(xpb + (((size_t)(hb16 * 2) * 16 + gmt) * 64 + l) * 64);
        const float* x1 = (const float*)(xpb + (((size_t)(hb16 * 2 + 1) * 16 + gmt) * 64 + l) * 64);
#pragma unroll
        for (int q = 0; q < 4; ++q) {
          f32x4 v0 = *(const f32x4*)(x0 + q * 4);
          f32x4 v1 = *(const f32x4*)(x1 + q * 4);
#pragma unroll
          for (int e = 0; e < 4; ++e) { p0[q * 4 + e] += v0[e]; p1[q * 4 + e] += v1[e]; }
        }
      }
      float* cb = (float*)(cfb + (((size_t)hb16 * 16 + gmt) * 64 + l) * 64);
      f32x4 cq[4];
#pragma unroll
      for (int q = 0; q < 4; ++q) cq[q] = *(const f32x4*)(cb + q * 4);
#pragma unroll
      for (int r = 0; r < 16; ++r) {
        float a0 = p0[r], a1 = p1[r];
        float y0 = __shfl_xor(a0, 16);
        float y1 = __shfl_xor(a1, 16);
        float vi = j16 ? y0 : a0;
        float vf = j16 ? a0 : y0;
        float vg = j16 ? y1 : a1;
        float vo = j16 ? a1 : y1;
        float co = cq[r >> 2][r & 3];
        float cn = sigf(vf) * co + sigf(vi) * tanhf_(vg);
        cq[r >> 2][r & 3] = cn;
        float hv = sigf(vo) * tanhf_(cn);
        const int rr = (r & 3) + 8 * (r >> 2) + 4 * khalf;
        *(unsigned short*)(tl + m * 1024 + rr * 32 + hc * 2) = f2bf(hv);
      }
#pragma unroll
      for (int q = 0; q < 4; ++q) *(f32x4*)(cb + q * 4) = cq[q];
    }
#pragma unroll
    for (int m = 0; m < 2; ++m) {
      short8 hv = *reinterpret_cast<const short8*>(tl + m * 1024 + (l & 31) * 32 + khalf * 16);
      *reinterpret_cast<short8*>(Ho + (((size_t)(gmt0 + m) * 64 + hb16) * 64 + l) * 16) = hv;
    }
  } else if (role == 2) {
    char* xpo = xp + (size_t)(t & 1) * 8388608;
#pragma unroll
    for (int m = 0; m < 2; ++m) {
      float* xo0 = (float*)(xpo + (((size_t)(hb16 * 2) * 16 + gmt0 + m) * 64 + l) * 64);
      float* xo1 = (float*)(xpo + (((size_t)(hb16 * 2 + 1) * 16 + gmt0 + m) * 64 + l) * 64);
#pragma unroll
      for (int q = 0; q < 4; ++q) {
        f32x4 v0 = { acc0[m][q * 4], acc0[m][q * 4 + 1], acc0[m][q * 4 + 2], acc0[m][q * 4 + 3] };
        f32x4 v1 = { acc1[m][q * 4], acc1[m][q * 4 + 1], acc1[m][q * 4 + 2], acc1[m][q * 4 + 3] };
        *(f32x4*)(xo0 + q * 4) = v0;
        *(f32x4*)(xo1 + q * 4) = v1;
      }
    }
  } else {
#pragma unroll
    for (int m = 0; m < 2; ++m) {
#pragma unroll
      for (int nt = 0; nt < 2; ++nt) {
        const int o = nt * 32 + (l & 31);
        const float bov = nt ? bo1 : bo0;
        if (o < OUT_) {
#pragma unroll
          for (int r = 0; r < 16; ++r) {
            const int rr = (r & 3) + 8 * (r >> 2) + 4 * khalf;
            const int bb = (gmt0 + m) * 32 + rr;
            const float pa = nt ? acc1[m][r] : acc0[m][r];
            out[((size_t)bb * S_ + t) * OUT_ + o] = sigf(pa + bov);
          }
        }
      }
    }
  }
}

// ---------------------------------------------------------------------------
extern "C" void kernel_launch(void* const* d_in, const int* in_sizes, int n_in,
                              void* d_out, int out_size, void* d_ws, size_t ws_size,
                              hipStream_t stream) {
  const float* z      = (const float*)d_in[0];
  const float* W_hid  = (const float*)d_in[1];
  const float* b_hid  = (const float*)d_in[2];
  const float* W_cell = (const float*)d_in[3];
  const float* b_cell = (const float*)d_in[4];
  // d_in[5] = W_ih0: multiplied by zeros in the reference -> unused
  const float* W_hh0  = (const float*)d_in[6];
  const float* b_ih0  = (const float*)d_in[7];
  const float* b_hh0  = (const float*)d_in[8];
  const float* W_ih1  = (const float*)d_in[9];
  const float* W_hh1  = (const float*)d_in[10];
  const float* b_ih1  = (const float*)d_in[11];
  const float* b_hh1  = (const float*)d_in[12];
  const float* W_out  = (const float*)d_in[13];
  const float* b_out  = (const float*)d_in[14];
  float* out = (float*)d_out;

  char* ws = (char*)d_ws;
  float*          B0P   = (float*)(ws + 4096);                    // 16 KiB
  float*          B1P   = (float*)(ws + 20480);                   // 16 KiB
  unsigned short* WOUTp = (unsigned short*)(ws + 65536);          // 128 KiB
  unsigned short* ZFp   = (unsigned short*)(ws + 196608);         // 64 KiB
  unsigned short* WIp   = (unsigned short*)(ws + 262144);         // 512 KiB
  unsigned short* W0p   = (unsigned short*)(ws + (1ull << 20));   // 8 MiB
  unsigned short* W1Hp  = (unsigned short*)(ws + (9ull << 20));   // 8 MiB
  unsigned short* W1Xp  = (unsigned short*)(ws + (17ull << 20));  // 8 MiB
  char*           H1F   = ws + (25ull << 20);                     // 2 MiB (2 slots)
  char*           H2F   = ws + (27ull << 20);                     // 2 MiB
  char*           XP    = ws + (29ull << 20);                     // 16 MiB (2 slots)
  char*           C0F   = ws + (45ull << 20);                     // 4 MiB
  char*           C1F   = ws + (49ull << 20);                     // 4 MiB

  pack_gate_kernel<<<2048, 256, 0, stream>>>(W_hh0, W0p);
  pack_gate_kernel<<<2048, 256, 0, stream>>>(W_hh1, W1Hp);
  pack_gate_kernel<<<2048, 256, 0, stream>>>(W_ih1, W1Xp);
  pack_nat_kernel<<<32, 256, 0, stream>>>(W_out, WOUTp, 2, 64, 1024, 0, 49);
  pack_nat_kernel<<<16, 256, 0, stream>>>(z, ZFp, 16, 4, 64, 0, 512);
  pack_nat_kernel<<<32, 256, 0, stream>>>(W_hid,  WIp,          32, 4, 64, 0,    1024);
  pack_nat_kernel<<<32, 256, 0, stream>>>(W_hid,  WIp + 65536,  32, 4, 64, 1024, 1024);
  pack_nat_kernel<<<32, 256, 0, stream>>>(W_cell, WIp + 131072, 32, 4, 64, 0,    1024);
  pack_nat_kernel<<<32, 256, 0, stream>>>(W_cell, WIp + 196608, 32, 4, 64, 1024, 1024);
  prep_bias_kernel<<<16, 256, 0, stream>>>(b_ih0, b_hh0, b_ih1, b_hh1, B0P, B1P);
  init_gemm_kernel<<<64, 256, 0, stream>>>(ZFp, WIp, b_hid, b_cell, H1F, H2F, C0F, C1F);

  static bool attr_set = false;
  if (!attr_set) {
    hipFuncSetAttribute((const void*)step_kernel,
                        hipFuncAttributeMaxDynamicSharedMemorySize, 147456);
    attr_set = true;
  }
  for (int k = 0; k < 131; ++k)
    step_kernel<<<NWG_, 512, 147456, stream>>>(
        k, W0p, W1Hp, W1Xp, WOUTp, B0P, B1P, b_out,
        H1F, H2F, XP, C0F, C1F, out);
}